// Round 4
// baseline (891.365 us; speedup 1.0000x reference)
//
#include <hip/hip_runtime.h>
#include <hip/hip_bf16.h>
#include <math.h>

// ---------------------------------------------------------------------------
// GraphSAGE 3-layer, HIDDEN=64, mean aggregation.
// R4: FULLY FUSED layer kernel. out[n] = elu( mean_n(h[src]) @ Wl + b + h[n] @ Wr )
// computed per node in one wave: gather-mean h rows, then dual 64x64 dot
// against LDS-resident W (k-interleaved float4 layout -> coalesced b128 LDS
// reads + broadcast b128 v reads). Eliminates gemm_y and the 51MB y buffer.
// CSR build (count/scan/fill) unchanged from R2.
// ---------------------------------------------------------------------------

#define HID 64

// ---- CSR build ------------------------------------------------------------

__global__ void count_deg(const int* __restrict__ dst, int* __restrict__ cnt, int E) {
    int e = blockIdx.x * blockDim.x + threadIdx.x;
    if (e < E) atomicAdd(&cnt[dst[e]], 1);
}

__global__ void scan_partials(const int* __restrict__ cnt, int* __restrict__ bsum, int n) {
    __shared__ int lsum[256];
    int t = threadIdx.x;
    int base = blockIdx.x * 1024 + t * 4;
    int s = 0;
    if (base + 3 < n) {
        int4 v = *(const int4*)&cnt[base];
        s = v.x + v.y + v.z + v.w;
    } else {
        for (int i = 0; i < 4; ++i) if (base + i < n) s += cnt[base + i];
    }
    lsum[t] = s;
    __syncthreads();
    for (int off = 128; off > 0; off >>= 1) {
        if (t < off) lsum[t] += lsum[t + off];
        __syncthreads();
    }
    if (t == 0) bsum[blockIdx.x] = lsum[0];
}

__global__ void scan_tops(int* __restrict__ bsum, int* __restrict__ offs_last,
                          int nb, int E) {
    __shared__ int s[128];
    int t = threadIdx.x;
    s[t] = (t < nb) ? bsum[t] : 0;
    __syncthreads();
    for (int off = 1; off < 128; off <<= 1) {
        int v = (t >= off) ? s[t - off] : 0;
        __syncthreads();
        s[t] += v;
        __syncthreads();
    }
    if (t < nb) bsum[t] = (t == 0) ? 0 : s[t - 1];
    if (t == 0) *offs_last = E;
}

__global__ void scan_write(const int* __restrict__ cnt, const int* __restrict__ bsum,
                           int* __restrict__ offs, float* __restrict__ invd, int n) {
    __shared__ int lsum[256];
    int t = threadIdx.x;
    int base = blockIdx.x * 1024 + t * 4;
    int v0 = 0, v1 = 0, v2 = 0, v3 = 0;
    bool full = (base + 3 < n);
    if (full) {
        int4 v = *(const int4*)&cnt[base];
        v0 = v.x; v1 = v.y; v2 = v.z; v3 = v.w;
    } else {
        if (base     < n) v0 = cnt[base];
        if (base + 1 < n) v1 = cnt[base + 1];
        if (base + 2 < n) v2 = cnt[base + 2];
        if (base + 3 < n) v3 = cnt[base + 3];
    }
    int ts = v0 + v1 + v2 + v3;
    lsum[t] = ts;
    __syncthreads();
    for (int off = 1; off < 256; off <<= 1) {
        int u = (t >= off) ? lsum[t - off] : 0;
        __syncthreads();
        lsum[t] += u;
        __syncthreads();
    }
    int ex = bsum[blockIdx.x] + ((t == 0) ? 0 : lsum[t - 1]);
    int o0 = ex, o1 = ex + v0, o2 = o1 + v1, o3 = o2 + v2;
    if (full) {
        *(int4*)&offs[base] = make_int4(o0, o1, o2, o3);
        float4 f = make_float4(1.0f / (float)max(v0, 1), 1.0f / (float)max(v1, 1),
                               1.0f / (float)max(v2, 1), 1.0f / (float)max(v3, 1));
        *(float4*)&invd[base] = f;
    } else {
        if (base     < n) { offs[base]     = o0; invd[base]     = 1.0f / (float)max(v0, 1); }
        if (base + 1 < n) { offs[base + 1] = o1; invd[base + 1] = 1.0f / (float)max(v1, 1); }
        if (base + 2 < n) { offs[base + 2] = o2; invd[base + 2] = 1.0f / (float)max(v2, 1); }
        if (base + 3 < n) { offs[base + 3] = o3; invd[base + 3] = 1.0f / (float)max(v3, 1); }
    }
}

__global__ void fill_csr(const int* __restrict__ src, const int* __restrict__ dst,
                         int* __restrict__ cursor, const int* __restrict__ offs,
                         int* __restrict__ csr, int E) {
    int e = blockIdx.x * blockDim.x + threadIdx.x;
    if (e < E) {
        int d = dst[e];
        int p = atomicAdd(&cursor[d], 1);
        csr[offs[d] + p] = src[e];
    }
}

// ---- fused layer: gather-mean + dual 64x64 dot + bias + ELU ---------------
// 512 threads = 8 waves/block; one node per wave (grid-stride).
// W stored k-interleaved: W4[k4][f] = {W[4k4+0][f],...,W[4k4+3][f]} so the
// k-loop does coalesced ds_read_b128 on W and broadcast b128 on v.

__launch_bounds__(512)
__global__ void sage_layer(const float* __restrict__ h,
                           const int* __restrict__ offs, const int* __restrict__ csr,
                           const float* __restrict__ invd,
                           const float* __restrict__ Wl, const float* __restrict__ bl,
                           const float* __restrict__ Wr,
                           float* __restrict__ out, int nnodes) {
    __shared__ float4 Wl4[16][64];     // 16 KB
    __shared__ float4 Wr4[16][64];     // 16 KB
    __shared__ float  bl_s[64];
    __shared__ float4 vbuf[8][2][16];  // per-wave agg/hn vectors, 4 KB
    int tid = threadIdx.x;

    // stage W (coalesced global reads, scattered LDS b32 writes)
    for (int idx = tid; idx < 64 * 64; idx += 512) {
        int k = idx >> 6, f = idx & 63;
        (&Wl4[k >> 2][f].x)[k & 3] = Wl[idx];
        (&Wr4[k >> 2][f].x)[k & 3] = Wr[idx];
    }
    if (tid < 64) bl_s[tid] = bl[tid];
    __syncthreads();

    int lane = tid & 63;
    int w    = tid >> 6;
    int wid  = blockIdx.x * 8 + w;
    int nw   = gridDim.x * 8;
    float* vagg = (float*)&vbuf[w][0][0];
    float* vhn  = (float*)&vbuf[w][1][0];

    for (int n = wid; n < nnodes; n += nw) {
        int beg = offs[n], end = offs[n + 1];
        float a0 = 0.f, a1 = 0.f, a2 = 0.f, a3 = 0.f;
        int k = beg;
        for (; k + 4 <= end; k += 4) {
            int s0 = csr[k], s1 = csr[k + 1], s2 = csr[k + 2], s3 = csr[k + 3];
            a0 += h[(size_t)s0 * HID + lane];
            a1 += h[(size_t)s1 * HID + lane];
            a2 += h[(size_t)s2 * HID + lane];
            a3 += h[(size_t)s3 * HID + lane];
        }
        for (; k < end; ++k) a0 += h[(size_t)csr[k] * HID + lane];
        float agg = ((a0 + a1) + (a2 + a3)) * invd[n];
        float hn  = h[(size_t)n * HID + lane];

        // publish vectors for in-wave broadcast (no barrier: same-wave LDS,
        // lgkmcnt ordering guarantees visibility)
        vagg[lane] = agg;
        vhn[lane]  = hn;

        float c0 = bl_s[lane], c1 = 0.f, c2 = 0.f, c3 = 0.f;
        float c4 = 0.f, c5 = 0.f, c6 = 0.f, c7 = 0.f;
#pragma unroll
        for (int k4 = 0; k4 < 16; ++k4) {
            float4 va = vbuf[w][0][k4];     // broadcast
            float4 vh = vbuf[w][1][k4];     // broadcast
            float4 wl = Wl4[k4][lane];      // coalesced
            float4 wr = Wr4[k4][lane];      // coalesced
            c0 += va.x * wl.x; c1 += va.y * wl.y;
            c2 += va.z * wl.z; c3 += va.w * wl.w;
            c4 += vh.x * wr.x; c5 += vh.y * wr.y;
            c6 += vh.z * wr.z; c7 += vh.w * wr.w;
        }
        float acc = ((c0 + c1) + (c2 + c3)) + ((c4 + c5) + (c6 + c7));
        out[(size_t)n * HID + lane] = acc > 0.f ? acc : expm1f(acc);
    }
}

// ---- launch ---------------------------------------------------------------

extern "C" void kernel_launch(void* const* d_in, const int* in_sizes, int n_in,
                              void* d_out, int out_size, void* d_ws, size_t ws_size,
                              hipStream_t stream) {
    const float* x   = (const float*)d_in[0];
    const int*   ei  = (const int*)d_in[1];
    const float* Wl1 = (const float*)d_in[2];
    const float* bl1 = (const float*)d_in[3];
    const float* Wr1 = (const float*)d_in[4];
    const float* Wl2 = (const float*)d_in[5];
    const float* bl2 = (const float*)d_in[6];
    const float* Wr2 = (const float*)d_in[7];
    const float* Wl3 = (const float*)d_in[8];
    const float* bl3 = (const float*)d_in[9];
    const float* Wr3 = (const float*)d_in[10];
    float* out = (float*)d_out;

    int N = in_sizes[0] / HID;   // 100000
    int E = in_sizes[1] / 2;     // 1600000
    const int* src = ei;
    const int* dst = ei + E;

    // workspace layout (16B aligned)
    char* p = (char*)d_ws;
    float* hA     = (float*)p; p += (size_t)N * HID * sizeof(float);
    float* hB     = (float*)p; p += (size_t)N * HID * sizeof(float);
    int*   csr    = (int*)p;   p += (size_t)E * sizeof(int);
    int*   cnt    = (int*)p;   p += (size_t)N * sizeof(int);
    int*   cursor = (int*)p;   p += (size_t)N * sizeof(int);   // adjacent to cnt
    int*   offs   = (int*)p;   p += (size_t)(N + 4) * sizeof(int);
    float* invd   = (float*)p; p += (size_t)N * sizeof(float);
    int*   bsum   = (int*)p;   p += 256 * sizeof(int);

    hipMemsetAsync(cnt, 0, (size_t)N * 2 * sizeof(int), stream);

    int eb = (E + 255) / 256;
    int sb = (N + 1023) / 1024;
    count_deg<<<eb, 256, 0, stream>>>(dst, cnt, E);
    scan_partials<<<sb, 256, 0, stream>>>(cnt, bsum, N);
    scan_tops<<<1, 128, 0, stream>>>(bsum, &offs[N], sb, E);
    scan_write<<<sb, 256, 0, stream>>>(cnt, bsum, offs, invd, N);
    fill_csr<<<eb, 256, 0, stream>>>(src, dst, cursor, offs, csr, E);

    // 1024 blocks x 8 waves = 8192 waves = 32/CU (full occupancy; LDS 36KB -> 4 blk/CU)
    sage_layer<<<1024, 512, 0, stream>>>(x,  offs, csr, invd, Wl1, bl1, Wr1, hA,  N);
    sage_layer<<<1024, 512, 0, stream>>>(hA, offs, csr, invd, Wl2, bl2, Wr2, hB,  N);
    sage_layer<<<1024, 512, 0, stream>>>(hB, offs, csr, invd, Wl3, bl3, Wr3, out, N);
}